// Round 19
// baseline (187.419 us; speedup 1.0000x reference)
//
#include <hip/hip_runtime.h>
#include <math.h>

#define NN 50000
#define NNP 50176            // padded rows (block tail writes unguarded)
#define NE 600000
#define NG 64
#define INCH 768
#define HID 128

typedef __attribute__((ext_vector_type(8))) short bf16x8;
typedef __attribute__((ext_vector_type(4))) float f32x4;
typedef __attribute__((ext_vector_type(4))) unsigned int u32x4;
typedef unsigned short u16;
typedef unsigned int u32;
typedef unsigned long long u64;

__device__ __forceinline__ u16 f2bf(float v) {
    u32 u = __builtin_bit_cast(u32, v);
    u32 r = u + 0x7FFFu + ((u >> 16) & 1u);
    return (u16)(r >> 16);
}
__device__ __forceinline__ float bf2f(u16 h) {
    u32 u = ((u32)h) << 16;
    return __builtin_bit_cast(float, u);
}
__device__ __forceinline__ u32 cvtpk(float a, float b) {
    u32 r;
    asm("v_cvt_pk_bf16_f32 %0, %1, %2" : "=v"(r) : "v"(a), "v"(b));
    return r;
}
// async global->LDS, 16B per lane (dest = wave-uniform base + lane*16)
__device__ __forceinline__ void gl_lds16(const void* g, void* l) {
    __builtin_amdgcn_global_load_lds(
        (const __attribute__((address_space(1))) unsigned int*)g,
        (__attribute__((address_space(3))) unsigned int*)l, 16, 0, 0);
}

struct SplitA { bf16x8 h, l; };

template <bool RELU>
__device__ __forceinline__ SplitA splitA(float4 b0, float4 b1) {
    if (RELU) {
        b0.x = fmaxf(b0.x, 0.f); b0.y = fmaxf(b0.y, 0.f);
        b0.z = fmaxf(b0.z, 0.f); b0.w = fmaxf(b0.w, 0.f);
        b1.x = fmaxf(b1.x, 0.f); b1.y = fmaxf(b1.y, 0.f);
        b1.z = fmaxf(b1.z, 0.f); b1.w = fmaxf(b1.w, 0.f);
    }
    u32 h0 = cvtpk(b0.x, b0.y), h1 = cvtpk(b0.z, b0.w);
    u32 h2 = cvtpk(b1.x, b1.y), h3 = cvtpk(b1.z, b1.w);
    float r0 = b0.x - __builtin_bit_cast(float, h0 << 16);
    float r1 = b0.y - __builtin_bit_cast(float, h0 & 0xFFFF0000u);
    float r2 = b0.z - __builtin_bit_cast(float, h1 << 16);
    float r3 = b0.w - __builtin_bit_cast(float, h1 & 0xFFFF0000u);
    float r4 = b1.x - __builtin_bit_cast(float, h2 << 16);
    float r5 = b1.y - __builtin_bit_cast(float, h2 & 0xFFFF0000u);
    float r6 = b1.z - __builtin_bit_cast(float, h3 << 16);
    float r7 = b1.w - __builtin_bit_cast(float, h3 & 0xFFFF0000u);
    u32 e0 = cvtpk(r0, r1), e1 = cvtpk(r2, r3);
    u32 e2 = cvtpk(r4, r5), e3 = cvtpk(r6, r7);
    SplitA s;
    s.h = __builtin_bit_cast(bf16x8, (u32x4){h0, h1, h2, h3});
    s.l = __builtin_bit_cast(bf16x8, (u32x4){e0, e1, e2, e3});
    return s;
}

// elementwise relu on 8 packed bf16 (exact)
__device__ __forceinline__ bf16x8 relu8(bf16x8 a) {
    u32x4 u = __builtin_bit_cast(u32x4, a);
#pragma unroll
    for (int i = 0; i < 4; i++) {
        u32 x = u[i];
        u32 lo = (x & 0x8000u) ? 0u : (x & 0x0000FFFFu);
        u32 hi = (x & 0x80000000u) ? 0u : (x & 0xFFFF0000u);
        u[i] = lo | hi;
    }
    return __builtin_bit_cast(bf16x8, u);
}

// ---------------------------------------------------------------------------
// FUSED PREP (one dispatch, 512 thr/block, branch by block range):
//  [0,98)    zero counts
//  [98,162)  cond_gemm: condW[g] = SE[g] @ W1[768:]  (8-way ILP K-chain)
//  [162,186) wt_pack W1 (24*512 items)
//  [186,190) wt_pack W2 (4*512 items)
// ---------------------------------------------------------------------------
__device__ __forceinline__ void wt_pack_item(const float* __restrict__ W,
                                             u16* __restrict__ P, int tid) {
    int l = tid & 63;
    int f = (tid >> 6) & 7;
    int c = tid >> 9;
    int n = f * 16 + (l & 15);
    int kb = c * 32 + ((l >> 4) & 3) * 8;
    u64 h0 = 0, h1 = 0, l0 = 0, l1 = 0;
#pragma unroll
    for (int e = 0; e < 8; e++) {
        float v = W[(size_t)(kb + e) * HID + n];
        u16 h = f2bf(v);
        u16 r = f2bf(v - bf2f(h));
        if (e < 4) { h0 |= (u64)h << (16 * e);       l0 |= (u64)r << (16 * e); }
        else       { h1 |= (u64)h << (16 * (e - 4)); l1 |= (u64)r << (16 * (e - 4)); }
    }
    size_t base = (size_t)c * 8192 + (size_t)f * 512 + l * 8;
    *(u64*)&P[base]          = h0;
    *(u64*)&P[base + 4]      = h1;
    *(u64*)&P[base + 4096]   = l0;
    *(u64*)&P[base + 4100]   = l1;
}

__global__ __launch_bounds__(512)
void prep_fused(int* __restrict__ counts,
                const float* __restrict__ SE, const float* __restrict__ W1,
                const float* __restrict__ W2, float* __restrict__ condW,
                u16* __restrict__ W1p, u16* __restrict__ W2p) {
    const int b = blockIdx.x, t = threadIdx.x;
    if (b < 98) {
        int i = b * 512 + t;
        if (i < NN) counts[i] = 0;
    } else if (b < 162) {
        __shared__ float se[INCH];
        __shared__ float part[4][HID];
        int g = b - 98;
        for (int i = t; i < INCH; i += 512) se[i] = SE[g * INCH + i];
        __syncthreads();
        int col = t & 127, ks = t >> 7;
        const float* Wb = W1 + (size_t)INCH * HID;
        const int kb = ks * 192;
        float p0 = 0.f, p1 = 0.f, p2 = 0.f, p3 = 0.f;
        float p4 = 0.f, p5 = 0.f, p6 = 0.f, p7 = 0.f;
#pragma unroll
        for (int k = 0; k < 192; k += 8) {
            p0 = fmaf(se[kb + k + 0], Wb[(size_t)(kb + k + 0) * HID + col], p0);
            p1 = fmaf(se[kb + k + 1], Wb[(size_t)(kb + k + 1) * HID + col], p1);
            p2 = fmaf(se[kb + k + 2], Wb[(size_t)(kb + k + 2) * HID + col], p2);
            p3 = fmaf(se[kb + k + 3], Wb[(size_t)(kb + k + 3) * HID + col], p3);
            p4 = fmaf(se[kb + k + 4], Wb[(size_t)(kb + k + 4) * HID + col], p4);
            p5 = fmaf(se[kb + k + 5], Wb[(size_t)(kb + k + 5) * HID + col], p5);
            p6 = fmaf(se[kb + k + 6], Wb[(size_t)(kb + k + 6) * HID + col], p6);
            p7 = fmaf(se[kb + k + 7], Wb[(size_t)(kb + k + 7) * HID + col], p7);
        }
        part[ks][col] = ((p0 + p1) + (p2 + p3)) + ((p4 + p5) + (p6 + p7));
        __syncthreads();
        if (t < HID)
            condW[g * HID + t] = part[0][t] + part[1][t] + part[2][t] + part[3][t];
    } else if (b < 186) {
        wt_pack_item(W1, W1p, (b - 162) * 512 + t);
    } else {
        wt_pack_item(W2, W2p, (b - 186) * 512 + t);
    }
}

// ---------------------------------------------------------------------------
__global__ void deg_count(const int* __restrict__ dst, int* counts) {
    int e = blockIdx.x * blockDim.x + threadIdx.x;
    if (e < NE) atomicAdd(&counts[dst[e]], 1);
}

// ---------------------------------------------------------------------------
// CSR build (pscan1 also emits dinv = rsqrt(deg+1))
// ---------------------------------------------------------------------------
__global__ void pscan1(const int* __restrict__ counts, int* __restrict__ row_start,
                       int* __restrict__ bsum, float* __restrict__ dinv) {
    __shared__ int sm[256];
    int t = threadIdx.x;
    int i = blockIdx.x * 256 + t;
    int v = (i < NN) ? counts[i] : 0;
    if (i < NN) dinv[i] = rsqrtf((float)v + 1.0f);
    sm[t] = v;
    __syncthreads();
#pragma unroll
    for (int off = 1; off < 256; off <<= 1) {
        int add = (t >= off) ? sm[t - off] : 0;
        __syncthreads();
        sm[t] += add;
        __syncthreads();
    }
    row_start[i] = sm[t] - v;
    if (t == 255) bsum[blockIdx.x] = sm[t];
}

__global__ void pscan23(int* __restrict__ row_start, const int* __restrict__ bsum,
                        int* __restrict__ cursor, int nb) {
    __shared__ int sm[256];
    int t = threadIdx.x, b = blockIdx.x;
    int v = (t < nb) ? bsum[t] : 0;
    sm[t] = v;
    __syncthreads();
#pragma unroll
    for (int off = 1; off < 256; off <<= 1) {
        int add = (t >= off) ? sm[t - off] : 0;
        __syncthreads();
        sm[t] += add;
        __syncthreads();
    }
    int blkoff = (b == 0) ? 0 : sm[b - 1];   // exclusive prefix for this block
    int i = b * 256 + t;
    int val = row_start[i] + blkoff;
    row_start[i] = val;
    if (i < NN) cursor[i] = val;
}

__global__ void csr_fill(const int* __restrict__ src, const int* __restrict__ dst,
                         int* __restrict__ cursor, int* __restrict__ csr_src) {
    int e = blockIdx.x * blockDim.x + threadIdx.x;
    if (e < NE) {
        int pos = atomicAdd(&cursor[dst[e]], 1);
        csr_src[pos] = src[e];
    }
}

// ---------------------------------------------------------------------------
// LAYER-1 GEMM, pipelined, A-prefetch depth 3 (GUARDED issues, exact counts):
//   u1(bf16) = (x @ W1[:768] + condW[batch]) * dinv
// (R17-verified: guarded loads, waits 4/8/12/8/0.)
// ---------------------------------------------------------------------------
__global__ __launch_bounds__(256, 2)
void mfma_gemm1(const float* __restrict__ A, const u16* __restrict__ P,
                u16* __restrict__ Cbf, const float* __restrict__ condW,
                const int* __restrict__ batch, const float* __restrict__ dinv,
                int M) {
    constexpr int K = INCH;
    constexpr int NC = K / 32;       // 24
    __shared__ u16 smem[24576];      // 3 x 16KB ring; epilogue reuses
    const int t = threadIdx.x;
    const int w = t >> 6;
    const int l = t & 63;
    const int l16 = l & 15;
    const int lq = l >> 4;
    const int m0 = blockIdx.x * 128;

    const int r0 = m0 + w * 32 + l16;
    const int r1 = r0 + 16;
    const int rc0 = r0 < M ? r0 : M - 1;
    const int rc1 = r1 < M ? r1 : M - 1;
    const float* Apf0 = A + (size_t)rc0 * K + lq * 8;
    const float* Apf1 = A + (size_t)rc1 * K + lq * 8;
    const char* Pb = (const char*)P + t * 16;

    f32x4 acc[2][8] = {};
    float4 ab[3][4];                 // 3-deep A buffers (static idx post-unroll)

#pragma unroll
    for (int d = 0; d < 3; d++) {
        ab[d][0] = *(const float4*)(Apf0 + d * 32);
        ab[d][1] = *(const float4*)(Apf0 + d * 32 + 4);
        ab[d][2] = *(const float4*)(Apf1 + d * 32);
        ab[d][3] = *(const float4*)(Apf1 + d * 32 + 4);
    }
    __builtin_amdgcn_sched_barrier(0);
    {
        char* d0 = (char*)smem + t * 16;
#pragma unroll
        for (int i = 0; i < 4; i++) gl_lds16(Pb + i * 4096, d0 + i * 4096);
        char* d1 = (char*)smem + 16384 + t * 16;
#pragma unroll
        for (int i = 0; i < 4; i++) gl_lds16(Pb + 16384 + i * 4096, d1 + i * 4096);
    }
    __builtin_amdgcn_sched_barrier(0);

#pragma unroll
    for (int c = 0; c < NC; ++c) {
        if (c == 0)
            asm volatile("s_waitcnt vmcnt(4)" ::: "memory");
        else if (c == 1 || c == NC - 2)
            asm volatile("s_waitcnt vmcnt(8)" ::: "memory");
        else if (c == NC - 1)
            asm volatile("s_waitcnt vmcnt(0)" ::: "memory");
        else
            asm volatile("s_waitcnt vmcnt(12)" ::: "memory");
        __builtin_amdgcn_s_barrier();
        __builtin_amdgcn_sched_barrier(0);

        const int slot = (c % 3) * 8192;       // u16 units
        if (c + 2 < NC) {
            const int nq = ((c + 2) % 3) * 16384;   // byte offset
            const char* src = (const char*)P + (size_t)(c + 2) * 16384 + t * 16;
            char* d = (char*)smem + nq + t * 16;
#pragma unroll
            for (int i = 0; i < 4; i++) gl_lds16(src + i * 4096, d + i * 4096);
        }
        __builtin_amdgcn_sched_barrier(0);

        const int d = c % 3;
        SplitA s0 = splitA<false>(ab[d][0], ab[d][1]);
        SplitA s1 = splitA<false>(ab[d][2], ab[d][3]);
        if (c + 3 < NC) {
            ab[d][0] = *(const float4*)(Apf0 + (c + 3) * 32);
            ab[d][1] = *(const float4*)(Apf0 + (c + 3) * 32 + 4);
            ab[d][2] = *(const float4*)(Apf1 + (c + 3) * 32);
            ab[d][3] = *(const float4*)(Apf1 + (c + 3) * 32 + 4);
        }
        __builtin_amdgcn_sched_barrier(0);

        bf16x8 bh[8], bl[8];
#pragma unroll
        for (int f = 0; f < 8; f++)
            bh[f] = *(const bf16x8*)&smem[slot + f * 512 + l * 8];
#pragma unroll
        for (int f = 0; f < 8; f++)
            bl[f] = *(const bf16x8*)&smem[slot + 4096 + f * 512 + l * 8];

#pragma unroll
        for (int f = 0; f < 8; f++) {
            acc[0][f] = __builtin_amdgcn_mfma_f32_16x16x32_bf16(s0.h, bh[f], acc[0][f], 0, 0, 0);
            acc[1][f] = __builtin_amdgcn_mfma_f32_16x16x32_bf16(s1.h, bh[f], acc[1][f], 0, 0, 0);
        }
#pragma unroll
        for (int f = 0; f < 8; f++) {
            acc[0][f] = __builtin_amdgcn_mfma_f32_16x16x32_bf16(s0.l, bh[f], acc[0][f], 0, 0, 0);
            acc[1][f] = __builtin_amdgcn_mfma_f32_16x16x32_bf16(s1.l, bh[f], acc[1][f], 0, 0, 0);
        }
#pragma unroll
        for (int f = 0; f < 8; f++) {
            acc[0][f] = __builtin_amdgcn_mfma_f32_16x16x32_bf16(s0.h, bl[f], acc[0][f], 0, 0, 0);
            acc[1][f] = __builtin_amdgcn_mfma_f32_16x16x32_bf16(s1.h, bl[f], acc[1][f], 0, 0, 0);
        }
    }
    __syncthreads();   // ring fully consumed; reuse LDS for epilogue

    u16* lds = smem + w * 4224;   // 32 rows x 132 u16
#pragma unroll
    for (int s = 0; s < 2; s++) {
#pragma unroll
        for (int j = 0; j < 4; j++) {
            int rl = s * 16 + lq * 4 + j;
            int grow = m0 + w * 32 + rl;
            int gs = grow < M ? grow : M - 1;
            float scale = dinv[gs];
            int gb = batch[gs];
#pragma unroll
            for (int f = 0; f < 8; f++) {
                float v = acc[s][f][j] + condW[gb * HID + f * 16 + l16];
                lds[rl * 132 + f * 16 + l16] = f2bf(v * scale);
            }
        }
    }
#pragma unroll
    for (int pass = 0; pass < 8; pass++) {
        int row = pass * 4 + lq;
        bf16x8 v = *(const bf16x8*)&lds[row * 132 + l16 * 8];
        *(bf16x8*)&Cbf[(size_t)(m0 + w * 32 + row) * HID + l16 * 8] = v;
    }
}

// ---------------------------------------------------------------------------
// LAYER-2 GEMM (R15/R17-verified pipelined template, ABF16 path):
//   u2(bf16) = (relu(h1bf) @ W2) * dinv
// ---------------------------------------------------------------------------
__global__ __launch_bounds__(256, 2)
void mfma_gemm2(const u16* __restrict__ Av, const u16* __restrict__ P,
                u16* __restrict__ Cbf, const float* __restrict__ dinv, int M) {
    constexpr int K = HID;
    constexpr int NC = K / 32;       // 4
    constexpr int AOPS = 2;
    __shared__ u16 smem[24576];
    const int t = threadIdx.x;
    const int w = t >> 6;
    const int l = t & 63;
    const int l16 = l & 15;
    const int lq = l >> 4;
    const int m0 = blockIdx.x * 128;

    const int r0 = m0 + w * 32 + l16;
    const int r1 = r0 + 16;
    const int rc0 = r0 < M ? r0 : M - 1;
    const int rc1 = r1 < M ? r1 : M - 1;
    const u16* Apb0 = Av + (size_t)rc0 * K + lq * 8;
    const u16* Apb1 = Av + (size_t)rc1 * K + lq * 8;
    const char* Pb = (const char*)P + t * 16;

    f32x4 acc[2][8] = {};

    bf16x8 ab0 = *(const bf16x8*)Apb0;
    bf16x8 ab1 = *(const bf16x8*)Apb1;
    __builtin_amdgcn_sched_barrier(0);
    {
        char* d0 = (char*)smem + t * 16;
#pragma unroll
        for (int i = 0; i < 4; i++) gl_lds16(Pb + i * 4096, d0 + i * 4096);
        char* d1 = (char*)smem + 16384 + t * 16;
#pragma unroll
        for (int i = 0; i < 4; i++) gl_lds16(Pb + 16384 + i * 4096, d1 + i * 4096);
    }
    __builtin_amdgcn_sched_barrier(0);

    int slot = 0;
    for (int c = 0; c < NC; ++c) {
        if (c == 0)
            asm volatile("s_waitcnt vmcnt(4)" ::: "memory");
        else if (c == NC - 1)
            asm volatile("s_waitcnt vmcnt(%0)" :: "i"(AOPS) : "memory");
        else
            asm volatile("s_waitcnt vmcnt(%0)" :: "i"(AOPS + 4) : "memory");
        __builtin_amdgcn_s_barrier();
        __builtin_amdgcn_sched_barrier(0);

        bf16x8 nb0 = ab0, nb1 = ab1;
        if (c + 1 < NC) {
            nb0 = *(const bf16x8*)(Apb0 + (c + 1) * 32);
            nb1 = *(const bf16x8*)(Apb1 + (c + 1) * 32);
        }
        __builtin_amdgcn_sched_barrier(0);
        if (c + 2 < NC) {
            int nq = slot + 16384;
            if (nq >= 24576) nq -= 24576;
            const char* src = (const char*)P + (size_t)(c + 2) * 16384 + t * 16;
            char* d = (char*)smem + (size_t)nq * 2 + t * 16;
#pragma unroll
            for (int i = 0; i < 4; i++) gl_lds16(src + i * 4096, d + i * 4096);
        }
        __builtin_amdgcn_sched_barrier(0);

        bf16x8 bh[8], bl[8];
#pragma unroll
        for (int f = 0; f < 8; f++)
            bh[f] = *(const bf16x8*)&smem[slot + f * 512 + l * 8];
#pragma unroll
        for (int f = 0; f < 8; f++)
            bl[f] = *(const bf16x8*)&smem[slot + 4096 + f * 512 + l * 8];

        bf16x8 h0 = relu8(ab0);
        bf16x8 h1 = relu8(ab1);
#pragma unroll
        for (int f = 0; f < 8; f++) {
            acc[0][f] = __builtin_amdgcn_mfma_f32_16x16x32_bf16(h0, bh[f], acc[0][f], 0, 0, 0);
            acc[1][f] = __builtin_amdgcn_mfma_f32_16x16x32_bf16(h1, bh[f], acc[1][f], 0, 0, 0);
        }
#pragma unroll
        for (int f = 0; f < 8; f++) {
            acc[0][f] = __builtin_amdgcn_mfma_f32_16x16x32_bf16(h0, bl[f], acc[0][f], 0, 0, 0);
            acc[1][f] = __builtin_amdgcn_mfma_f32_16x16x32_bf16(h1, bl[f], acc[1][f], 0, 0, 0);
        }

        ab0 = nb0; ab1 = nb1;
        slot += 8192;
        if (slot >= 24576) slot = 0;
    }
    __syncthreads();

    u16* lds = smem + w * 4224;
#pragma unroll
    for (int s = 0; s < 2; s++) {
#pragma unroll
        for (int j = 0; j < 4; j++) {
            int rl = s * 16 + lq * 4 + j;
            int grow = m0 + w * 32 + rl;
            int gs = grow < M ? grow : M - 1;
            float scale = dinv[gs];
#pragma unroll
            for (int f = 0; f < 8; f++)
                lds[rl * 132 + f * 16 + l16] = f2bf(acc[s][f][j] * scale);
        }
    }
#pragma unroll
    for (int pass = 0; pass < 8; pass++) {
        int row = pass * 4 + lq;
        bf16x8 v = *(const bf16x8*)&lds[row * 132 + l16 * 8];
        *(bf16x8*)&Cbf[(size_t)(m0 + w * 32 + row) * HID + l16 * 8] = v;
    }
}

// ---------------------------------------------------------------------------
// gather aggregation, QUARTER-WAVE per node (16 lanes, 4 u32 cols/lane):
//   o[d] = bias + dinv[d]*(u[d] + sum u[src])
// Per-column accumulation order identical to R18 -> MODE 0 bitwise-identical.
// 8/4/1 edge unroll; per-lane uint4 (16B) loads double outstanding bytes
// again (coalescing: 16 x 16B = 256B row).
// MODE 0: write o as packed bf16 (uint4/lane).  MODE 1: fused output head
// (8 local cols then width-16 shuffle; tree reorder = f32 noise only).
// ---------------------------------------------------------------------------
template <int MODE>
__global__ __launch_bounds__(512)
void agg_gather(const u32* __restrict__ u, const float* __restrict__ dinv,
                const int* __restrict__ row_start, const int* __restrict__ csr_src,
                const float* __restrict__ bias, u32* __restrict__ outbf,
                const float* __restrict__ Wout, const float* __restrict__ bout,
                float* __restrict__ logits) {
    int node = blockIdx.x * 32 + (threadIdx.x >> 4);
    int lane = threadIdx.x & 15;
    if (node >= NN) return;
    int p = row_start[node], pend = row_start[node + 1];
    u32x4 pv = *(const u32x4*)&u[(size_t)node * 64 + lane * 4];
    float a0 = __builtin_bit_cast(float, pv[0] << 16);
    float a1 = __builtin_bit_cast(float, pv[0] & 0xFFFF0000u);
    float a2 = __builtin_bit_cast(float, pv[1] << 16);
    float a3 = __builtin_bit_cast(float, pv[1] & 0xFFFF0000u);
    float a4 = __builtin_bit_cast(float, pv[2] << 16);
    float a5 = __builtin_bit_cast(float, pv[2] & 0xFFFF0000u);
    float a6 = __builtin_bit_cast(float, pv[3] << 16);
    float a7 = __builtin_bit_cast(float, pv[3] & 0xFFFF0000u);
#define ACC4(vv)                                                \
    a0 += __builtin_bit_cast(float, (vv)[0] << 16);             \
    a1 += __builtin_bit_cast(float, (vv)[0] & 0xFFFF0000u);     \
    a2 += __builtin_bit_cast(float, (vv)[1] << 16);             \
    a3 += __builtin_bit_cast(float, (vv)[1] & 0xFFFF0000u);     \
    a4 += __builtin_bit_cast(float, (vv)[2] << 16);             \
    a5 += __builtin_bit_cast(float, (vv)[2] & 0xFFFF0000u);     \
    a6 += __builtin_bit_cast(float, (vv)[3] << 16);             \
    a7 += __builtin_bit_cast(float, (vv)[3] & 0xFFFF0000u);
    int p8 = p + ((pend - p) & ~7);
    for (; p < p8; p += 8) {
        int s0 = csr_src[p],     s1 = csr_src[p + 1];
        int s2 = csr_src[p + 2], s3 = csr_src[p + 3];
        int s4 = csr_src[p + 4], s5 = csr_src[p + 5];
        int s6 = csr_src[p + 6], s7 = csr_src[p + 7];
        u32x4 v0 = *(const u32x4*)&u[(size_t)s0 * 64 + lane * 4];
        u32x4 v1 = *(const u32x4*)&u[(size_t)s1 * 64 + lane * 4];
        u32x4 v2 = *(const u32x4*)&u[(size_t)s2 * 64 + lane * 4];
        u32x4 v3 = *(const u32x4*)&u[(size_t)s3 * 64 + lane * 4];
        u32x4 v4 = *(const u32x4*)&u[(size_t)s4 * 64 + lane * 4];
        u32x4 v5 = *(const u32x4*)&u[(size_t)s5 * 64 + lane * 4];
        u32x4 v6 = *(const u32x4*)&u[(size_t)s6 * 64 + lane * 4];
        u32x4 v7 = *(const u32x4*)&u[(size_t)s7 * 64 + lane * 4];
        ACC4(v0) ACC4(v1) ACC4(v2) ACC4(v3)
        ACC4(v4) ACC4(v5) ACC4(v6) ACC4(v7)
    }
    int p4 = p + ((pend - p) & ~3);
    for (; p < p4; p += 4) {
        int s0 = csr_src[p],     s1 = csr_src[p + 1];
        int s2 = csr_src[p + 2], s3 = csr_src[p + 3];
        u32x4 v0 = *(const u32x4*)&u[(size_t)s0 * 64 + lane * 4];
        u32x4 v1 = *(const u32x4*)&u[(size_t)s1 * 64 + lane * 4];
        u32x4 v2 = *(const u32x4*)&u[(size_t)s2 * 64 + lane * 4];
        u32x4 v3 = *(const u32x4*)&u[(size_t)s3 * 64 + lane * 4];
        ACC4(v0) ACC4(v1) ACC4(v2) ACC4(v3)
    }
    for (; p < pend; ++p) {
        int s = csr_src[p];
        u32x4 v = *(const u32x4*)&u[(size_t)s * 64 + lane * 4];
        ACC4(v)
    }
#undef ACC4
    float dd = dinv[node];
    float4 bb0 = *(const float4*)&bias[lane * 8];
    float4 bb1 = *(const float4*)&bias[lane * 8 + 4];
    float o0 = fmaf(dd, a0, bb0.x);
    float o1 = fmaf(dd, a1, bb0.y);
    float o2 = fmaf(dd, a2, bb0.z);
    float o3 = fmaf(dd, a3, bb0.w);
    float o4 = fmaf(dd, a4, bb1.x);
    float o5 = fmaf(dd, a5, bb1.y);
    float o6 = fmaf(dd, a6, bb1.z);
    float o7 = fmaf(dd, a7, bb1.w);
    if (MODE == 1) {
        float4 wv0 = *(const float4*)&Wout[lane * 8];
        float4 wv1 = *(const float4*)&Wout[lane * 8 + 4];
        float v = fmaxf(o0, 0.f) * wv0.x + fmaxf(o1, 0.f) * wv0.y +
                  fmaxf(o2, 0.f) * wv0.z + fmaxf(o3, 0.f) * wv0.w +
                  fmaxf(o4, 0.f) * wv1.x + fmaxf(o5, 0.f) * wv1.y +
                  fmaxf(o6, 0.f) * wv1.z + fmaxf(o7, 0.f) * wv1.w;
#pragma unroll
        for (int o = 8; o; o >>= 1) v += __shfl_down(v, o, 16);
        if (lane == 0) logits[node] = v + bout[0];
    } else {
        u32x4 r;
        r[0] = cvtpk(o0, o1);
        r[1] = cvtpk(o2, o3);
        r[2] = cvtpk(o4, o5);
        r[3] = cvtpk(o6, o7);
        *(u32x4*)&outbf[(size_t)node * 64 + lane * 4] = r;
    }
}

// ---------------------------------------------------------------------------
extern "C" void kernel_launch(void* const* d_in, const int* in_sizes, int n_in,
                              void* d_out, int out_size, void* d_ws, size_t ws_size,
                              hipStream_t stream) {
    const float* x     = (const float*)d_in[0];
    const int*   ei    = (const int*)d_in[1];
    const float* se    = (const float*)d_in[2];
    const int*   batch = (const int*)d_in[3];
    const float* W1    = (const float*)d_in[4];
    const float* b1    = (const float*)d_in[5];
    const float* W2    = (const float*)d_in[6];
    const float* b2    = (const float*)d_in[7];
    const float* Wout  = (const float*)d_in[8];
    const float* bout  = (const float*)d_in[9];
    float* logits = (float*)d_out;

    const int* srcp = ei;
    const int* dstp = ei + NE;

    // workspace carve (float offsets; 16B-aligned)
    float* ws       = (float*)d_ws;
    float* dinv     = ws;                        // 50176
    float* condW    = ws + 50176;                // 8192
    u16*   W1p      = (u16*)(ws + 58368);        // 98304 f
    u16*   W2p      = (u16*)(ws + 156672);       // 16384 f
    int*   counts   = (int*)(ws + 173056);       // 50176 (reused as cursor)
    int*   row_st   = (int*)(ws + 223232);       // 50176
    int*   csr_src  = (int*)(ws + 273408);       // 600000
    int*   bsum     = (int*)(ws + 873408);       // 256
    float* bufA     = ws + 873664;               // NNP*128 f region

    u16* ubf  = (u16*)bufA;                      // u (bf16), both layers
    u16* h1bf = (u16*)(bufA + (size_t)NNP * 64); // h1 (bf16)

    const int NB = (NN + 255) / 256;  // 196

    // fused prep: zero counts | condW | W1 pack | W2 pack  (one dispatch)
    prep_fused<<<190, 512, 0, stream>>>(counts, se, W1, W2, condW, W1p, W2p);

    // degree + CSR build
    deg_count<<<(NE + 255) / 256, 256, 0, stream>>>(dstp, counts);
    pscan1<<<NB, 256, 0, stream>>>(counts, row_st, bsum, dinv);
    pscan23<<<NB, 256, 0, stream>>>(row_st, bsum, counts, NB);
    csr_fill<<<(NE + 255) / 256, 256, 0, stream>>>(srcp, dstp, counts, csr_src);

    const int GB = (NN + 127) / 128;   // 391

    // layer 1 (pipelined, A-depth 3): u1(bf16) = (x @ W1[:768] + cond) * dinv
    mfma_gemm1<<<GB, 256, 0, stream>>>(x, W1p, ubf, condW, batch, dinv, NN);
    agg_gather<0><<<(NN + 31) / 32, 512, 0, stream>>>(
        (const u32*)ubf, dinv, row_st, csr_src, b1, (u32*)h1bf,
        nullptr, nullptr, nullptr);

    // layer 2 (pipelined): u2(bf16) = (relu(h1bf) @ W2) * dinv ; gather + head
    mfma_gemm2<<<GB, 256, 0, stream>>>(h1bf, W2p, ubf, dinv, NN);
    agg_gather<1><<<(NN + 31) / 32, 512, 0, stream>>>(
        (const u32*)ubf, dinv, row_st, csr_src, b2, nullptr, Wout, bout, logits);
}

// Round 20
// 183.080 us; speedup vs baseline: 1.0237x; 1.0237x over previous
//
#include <hip/hip_runtime.h>
#include <math.h>

#define NN 50000
#define NNP 50176            // padded rows (block tail writes unguarded)
#define NE 600000
#define NG 64
#define INCH 768
#define HID 128

typedef __attribute__((ext_vector_type(8))) short bf16x8;
typedef __attribute__((ext_vector_type(4))) float f32x4;
typedef __attribute__((ext_vector_type(4))) unsigned int u32x4;
typedef __attribute__((ext_vector_type(2))) unsigned int u32x2;
typedef unsigned short u16;
typedef unsigned int u32;
typedef unsigned long long u64;

__device__ __forceinline__ u16 f2bf(float v) {
    u32 u = __builtin_bit_cast(u32, v);
    u32 r = u + 0x7FFFu + ((u >> 16) & 1u);
    return (u16)(r >> 16);
}
__device__ __forceinline__ float bf2f(u16 h) {
    u32 u = ((u32)h) << 16;
    return __builtin_bit_cast(float, u);
}
__device__ __forceinline__ u32 cvtpk(float a, float b) {
    u32 r;
    asm("v_cvt_pk_bf16_f32 %0, %1, %2" : "=v"(r) : "v"(a), "v"(b));
    return r;
}
// async global->LDS, 16B per lane (dest = wave-uniform base + lane*16)
__device__ __forceinline__ void gl_lds16(const void* g, void* l) {
    __builtin_amdgcn_global_load_lds(
        (const __attribute__((address_space(1))) unsigned int*)g,
        (__attribute__((address_space(3))) unsigned int*)l, 16, 0, 0);
}

struct SplitA { bf16x8 h, l; };

template <bool RELU>
__device__ __forceinline__ SplitA splitA(float4 b0, float4 b1) {
    if (RELU) {
        b0.x = fmaxf(b0.x, 0.f); b0.y = fmaxf(b0.y, 0.f);
        b0.z = fmaxf(b0.z, 0.f); b0.w = fmaxf(b0.w, 0.f);
        b1.x = fmaxf(b1.x, 0.f); b1.y = fmaxf(b1.y, 0.f);
        b1.z = fmaxf(b1.z, 0.f); b1.w = fmaxf(b1.w, 0.f);
    }
    u32 h0 = cvtpk(b0.x, b0.y), h1 = cvtpk(b0.z, b0.w);
    u32 h2 = cvtpk(b1.x, b1.y), h3 = cvtpk(b1.z, b1.w);
    float r0 = b0.x - __builtin_bit_cast(float, h0 << 16);
    float r1 = b0.y - __builtin_bit_cast(float, h0 & 0xFFFF0000u);
    float r2 = b0.z - __builtin_bit_cast(float, h1 << 16);
    float r3 = b0.w - __builtin_bit_cast(float, h1 & 0xFFFF0000u);
    float r4 = b1.x - __builtin_bit_cast(float, h2 << 16);
    float r5 = b1.y - __builtin_bit_cast(float, h2 & 0xFFFF0000u);
    float r6 = b1.z - __builtin_bit_cast(float, h3 << 16);
    float r7 = b1.w - __builtin_bit_cast(float, h3 & 0xFFFF0000u);
    u32 e0 = cvtpk(r0, r1), e1 = cvtpk(r2, r3);
    u32 e2 = cvtpk(r4, r5), e3 = cvtpk(r6, r7);
    SplitA s;
    s.h = __builtin_bit_cast(bf16x8, (u32x4){h0, h1, h2, h3});
    s.l = __builtin_bit_cast(bf16x8, (u32x4){e0, e1, e2, e3});
    return s;
}

// elementwise relu on 8 packed bf16 (exact)
__device__ __forceinline__ bf16x8 relu8(bf16x8 a) {
    u32x4 u = __builtin_bit_cast(u32x4, a);
#pragma unroll
    for (int i = 0; i < 4; i++) {
        u32 x = u[i];
        u32 lo = (x & 0x8000u) ? 0u : (x & 0x0000FFFFu);
        u32 hi = (x & 0x80000000u) ? 0u : (x & 0xFFFF0000u);
        u[i] = lo | hi;
    }
    return __builtin_bit_cast(bf16x8, u);
}

// ---------------------------------------------------------------------------
// FUSED PREP (one dispatch, 512 thr/block, branch by block range):
//  [0,98)    zero counts
//  [98,162)  cond_gemm: condW[g] = SE[g] @ W1[768:]  (8-way ILP K-chain)
//  [162,186) wt_pack W1 (24*512 items)
//  [186,190) wt_pack W2 (4*512 items)
// ---------------------------------------------------------------------------
__device__ __forceinline__ void wt_pack_item(const float* __restrict__ W,
                                             u16* __restrict__ P, int tid) {
    int l = tid & 63;
    int f = (tid >> 6) & 7;
    int c = tid >> 9;
    int n = f * 16 + (l & 15);
    int kb = c * 32 + ((l >> 4) & 3) * 8;
    u64 h0 = 0, h1 = 0, l0 = 0, l1 = 0;
#pragma unroll
    for (int e = 0; e < 8; e++) {
        float v = W[(size_t)(kb + e) * HID + n];
        u16 h = f2bf(v);
        u16 r = f2bf(v - bf2f(h));
        if (e < 4) { h0 |= (u64)h << (16 * e);       l0 |= (u64)r << (16 * e); }
        else       { h1 |= (u64)h << (16 * (e - 4)); l1 |= (u64)r << (16 * (e - 4)); }
    }
    size_t base = (size_t)c * 8192 + (size_t)f * 512 + l * 8;
    *(u64*)&P[base]          = h0;
    *(u64*)&P[base + 4]      = h1;
    *(u64*)&P[base + 4096]   = l0;
    *(u64*)&P[base + 4100]   = l1;
}

__global__ __launch_bounds__(512)
void prep_fused(int* __restrict__ counts,
                const float* __restrict__ SE, const float* __restrict__ W1,
                const float* __restrict__ W2, float* __restrict__ condW,
                u16* __restrict__ W1p, u16* __restrict__ W2p) {
    const int b = blockIdx.x, t = threadIdx.x;
    if (b < 98) {
        int i = b * 512 + t;
        if (i < NN) counts[i] = 0;
    } else if (b < 162) {
        __shared__ float se[INCH];
        __shared__ float part[4][HID];
        int g = b - 98;
        for (int i = t; i < INCH; i += 512) se[i] = SE[g * INCH + i];
        __syncthreads();
        int col = t & 127, ks = t >> 7;
        const float* Wb = W1 + (size_t)INCH * HID;
        const int kb = ks * 192;
        float p0 = 0.f, p1 = 0.f, p2 = 0.f, p3 = 0.f;
        float p4 = 0.f, p5 = 0.f, p6 = 0.f, p7 = 0.f;
#pragma unroll
        for (int k = 0; k < 192; k += 8) {
            p0 = fmaf(se[kb + k + 0], Wb[(size_t)(kb + k + 0) * HID + col], p0);
            p1 = fmaf(se[kb + k + 1], Wb[(size_t)(kb + k + 1) * HID + col], p1);
            p2 = fmaf(se[kb + k + 2], Wb[(size_t)(kb + k + 2) * HID + col], p2);
            p3 = fmaf(se[kb + k + 3], Wb[(size_t)(kb + k + 3) * HID + col], p3);
            p4 = fmaf(se[kb + k + 4], Wb[(size_t)(kb + k + 4) * HID + col], p4);
            p5 = fmaf(se[kb + k + 5], Wb[(size_t)(kb + k + 5) * HID + col], p5);
            p6 = fmaf(se[kb + k + 6], Wb[(size_t)(kb + k + 6) * HID + col], p6);
            p7 = fmaf(se[kb + k + 7], Wb[(size_t)(kb + k + 7) * HID + col], p7);
        }
        part[ks][col] = ((p0 + p1) + (p2 + p3)) + ((p4 + p5) + (p6 + p7));
        __syncthreads();
        if (t < HID)
            condW[g * HID + t] = part[0][t] + part[1][t] + part[2][t] + part[3][t];
    } else if (b < 186) {
        wt_pack_item(W1, W1p, (b - 162) * 512 + t);
    } else {
        wt_pack_item(W2, W2p, (b - 186) * 512 + t);
    }
}

// ---------------------------------------------------------------------------
__global__ void deg_count(const int* __restrict__ dst, int* counts) {
    int e = blockIdx.x * blockDim.x + threadIdx.x;
    if (e < NE) atomicAdd(&counts[dst[e]], 1);
}

// ---------------------------------------------------------------------------
// CSR build (pscan1 also emits dinv = rsqrt(deg+1))
// ---------------------------------------------------------------------------
__global__ void pscan1(const int* __restrict__ counts, int* __restrict__ row_start,
                       int* __restrict__ bsum, float* __restrict__ dinv) {
    __shared__ int sm[256];
    int t = threadIdx.x;
    int i = blockIdx.x * 256 + t;
    int v = (i < NN) ? counts[i] : 0;
    if (i < NN) dinv[i] = rsqrtf((float)v + 1.0f);
    sm[t] = v;
    __syncthreads();
#pragma unroll
    for (int off = 1; off < 256; off <<= 1) {
        int add = (t >= off) ? sm[t - off] : 0;
        __syncthreads();
        sm[t] += add;
        __syncthreads();
    }
    row_start[i] = sm[t] - v;
    if (t == 255) bsum[blockIdx.x] = sm[t];
}

__global__ void pscan23(int* __restrict__ row_start, const int* __restrict__ bsum,
                        int* __restrict__ cursor, int nb) {
    __shared__ int sm[256];
    int t = threadIdx.x, b = blockIdx.x;
    int v = (t < nb) ? bsum[t] : 0;
    sm[t] = v;
    __syncthreads();
#pragma unroll
    for (int off = 1; off < 256; off <<= 1) {
        int add = (t >= off) ? sm[t - off] : 0;
        __syncthreads();
        sm[t] += add;
        __syncthreads();
    }
    int blkoff = (b == 0) ? 0 : sm[b - 1];   // exclusive prefix for this block
    int i = b * 256 + t;
    int val = row_start[i] + blkoff;
    row_start[i] = val;
    if (i < NN) cursor[i] = val;
}

__global__ void csr_fill(const int* __restrict__ src, const int* __restrict__ dst,
                         int* __restrict__ cursor, int* __restrict__ csr_src) {
    int e = blockIdx.x * blockDim.x + threadIdx.x;
    if (e < NE) {
        int pos = atomicAdd(&cursor[dst[e]], 1);
        csr_src[pos] = src[e];
    }
}

// ---------------------------------------------------------------------------
// LAYER-1 GEMM, pipelined, A-prefetch depth 3 (GUARDED issues, exact counts):
//   u1(bf16) = (x @ W1[:768] + condW[batch]) * dinv
// (R17-verified: guarded loads, waits 4/8/12/8/0.)
// ---------------------------------------------------------------------------
__global__ __launch_bounds__(256, 2)
void mfma_gemm1(const float* __restrict__ A, const u16* __restrict__ P,
                u16* __restrict__ Cbf, const float* __restrict__ condW,
                const int* __restrict__ batch, const float* __restrict__ dinv,
                int M) {
    constexpr int K = INCH;
    constexpr int NC = K / 32;       // 24
    __shared__ u16 smem[24576];      // 3 x 16KB ring; epilogue reuses
    const int t = threadIdx.x;
    const int w = t >> 6;
    const int l = t & 63;
    const int l16 = l & 15;
    const int lq = l >> 4;
    const int m0 = blockIdx.x * 128;

    const int r0 = m0 + w * 32 + l16;
    const int r1 = r0 + 16;
    const int rc0 = r0 < M ? r0 : M - 1;
    const int rc1 = r1 < M ? r1 : M - 1;
    const float* Apf0 = A + (size_t)rc0 * K + lq * 8;
    const float* Apf1 = A + (size_t)rc1 * K + lq * 8;
    const char* Pb = (const char*)P + t * 16;

    f32x4 acc[2][8] = {};
    float4 ab[3][4];                 // 3-deep A buffers (static idx post-unroll)

#pragma unroll
    for (int d = 0; d < 3; d++) {
        ab[d][0] = *(const float4*)(Apf0 + d * 32);
        ab[d][1] = *(const float4*)(Apf0 + d * 32 + 4);
        ab[d][2] = *(const float4*)(Apf1 + d * 32);
        ab[d][3] = *(const float4*)(Apf1 + d * 32 + 4);
    }
    __builtin_amdgcn_sched_barrier(0);
    {
        char* d0 = (char*)smem + t * 16;
#pragma unroll
        for (int i = 0; i < 4; i++) gl_lds16(Pb + i * 4096, d0 + i * 4096);
        char* d1 = (char*)smem + 16384 + t * 16;
#pragma unroll
        for (int i = 0; i < 4; i++) gl_lds16(Pb + 16384 + i * 4096, d1 + i * 4096);
    }
    __builtin_amdgcn_sched_barrier(0);

#pragma unroll
    for (int c = 0; c < NC; ++c) {
        if (c == 0)
            asm volatile("s_waitcnt vmcnt(4)" ::: "memory");
        else if (c == 1 || c == NC - 2)
            asm volatile("s_waitcnt vmcnt(8)" ::: "memory");
        else if (c == NC - 1)
            asm volatile("s_waitcnt vmcnt(0)" ::: "memory");
        else
            asm volatile("s_waitcnt vmcnt(12)" ::: "memory");
        __builtin_amdgcn_s_barrier();
        __builtin_amdgcn_sched_barrier(0);

        const int slot = (c % 3) * 8192;       // u16 units
        if (c + 2 < NC) {
            const int nq = ((c + 2) % 3) * 16384;   // byte offset
            const char* src = (const char*)P + (size_t)(c + 2) * 16384 + t * 16;
            char* d = (char*)smem + nq + t * 16;
#pragma unroll
            for (int i = 0; i < 4; i++) gl_lds16(src + i * 4096, d + i * 4096);
        }
        __builtin_amdgcn_sched_barrier(0);

        const int d = c % 3;
        SplitA s0 = splitA<false>(ab[d][0], ab[d][1]);
        SplitA s1 = splitA<false>(ab[d][2], ab[d][3]);
        if (c + 3 < NC) {
            ab[d][0] = *(const float4*)(Apf0 + (c + 3) * 32);
            ab[d][1] = *(const float4*)(Apf0 + (c + 3) * 32 + 4);
            ab[d][2] = *(const float4*)(Apf1 + (c + 3) * 32);
            ab[d][3] = *(const float4*)(Apf1 + (c + 3) * 32 + 4);
        }
        __builtin_amdgcn_sched_barrier(0);

        bf16x8 bh[8], bl[8];
#pragma unroll
        for (int f = 0; f < 8; f++)
            bh[f] = *(const bf16x8*)&smem[slot + f * 512 + l * 8];
#pragma unroll
        for (int f = 0; f < 8; f++)
            bl[f] = *(const bf16x8*)&smem[slot + 4096 + f * 512 + l * 8];

#pragma unroll
        for (int f = 0; f < 8; f++) {
            acc[0][f] = __builtin_amdgcn_mfma_f32_16x16x32_bf16(s0.h, bh[f], acc[0][f], 0, 0, 0);
            acc[1][f] = __builtin_amdgcn_mfma_f32_16x16x32_bf16(s1.h, bh[f], acc[1][f], 0, 0, 0);
        }
#pragma unroll
        for (int f = 0; f < 8; f++) {
            acc[0][f] = __builtin_amdgcn_mfma_f32_16x16x32_bf16(s0.l, bh[f], acc[0][f], 0, 0, 0);
            acc[1][f] = __builtin_amdgcn_mfma_f32_16x16x32_bf16(s1.l, bh[f], acc[1][f], 0, 0, 0);
        }
#pragma unroll
        for (int f = 0; f < 8; f++) {
            acc[0][f] = __builtin_amdgcn_mfma_f32_16x16x32_bf16(s0.h, bl[f], acc[0][f], 0, 0, 0);
            acc[1][f] = __builtin_amdgcn_mfma_f32_16x16x32_bf16(s1.h, bl[f], acc[1][f], 0, 0, 0);
        }
    }
    __syncthreads();   // ring fully consumed; reuse LDS for epilogue

    u16* lds = smem + w * 4224;   // 32 rows x 132 u16
#pragma unroll
    for (int s = 0; s < 2; s++) {
#pragma unroll
        for (int j = 0; j < 4; j++) {
            int rl = s * 16 + lq * 4 + j;
            int grow = m0 + w * 32 + rl;
            int gs = grow < M ? grow : M - 1;
            float scale = dinv[gs];
            int gb = batch[gs];
#pragma unroll
            for (int f = 0; f < 8; f++) {
                float v = acc[s][f][j] + condW[gb * HID + f * 16 + l16];
                lds[rl * 132 + f * 16 + l16] = f2bf(v * scale);
            }
        }
    }
#pragma unroll
    for (int pass = 0; pass < 8; pass++) {
        int row = pass * 4 + lq;
        bf16x8 v = *(const bf16x8*)&lds[row * 132 + l16 * 8];
        *(bf16x8*)&Cbf[(size_t)(m0 + w * 32 + row) * HID + l16 * 8] = v;
    }
}

// ---------------------------------------------------------------------------
// LAYER-2 GEMM (R15/R17-verified pipelined template, ABF16 path):
//   u2(bf16) = (relu(h1bf) @ W2) * dinv
// ---------------------------------------------------------------------------
__global__ __launch_bounds__(256, 2)
void mfma_gemm2(const u16* __restrict__ Av, const u16* __restrict__ P,
                u16* __restrict__ Cbf, const float* __restrict__ dinv, int M) {
    constexpr int K = HID;
    constexpr int NC = K / 32;       // 4
    constexpr int AOPS = 2;
    __shared__ u16 smem[24576];
    const int t = threadIdx.x;
    const int w = t >> 6;
    const int l = t & 63;
    const int l16 = l & 15;
    const int lq = l >> 4;
    const int m0 = blockIdx.x * 128;

    const int r0 = m0 + w * 32 + l16;
    const int r1 = r0 + 16;
    const int rc0 = r0 < M ? r0 : M - 1;
    const int rc1 = r1 < M ? r1 : M - 1;
    const u16* Apb0 = Av + (size_t)rc0 * K + lq * 8;
    const u16* Apb1 = Av + (size_t)rc1 * K + lq * 8;
    const char* Pb = (const char*)P + t * 16;

    f32x4 acc[2][8] = {};

    bf16x8 ab0 = *(const bf16x8*)Apb0;
    bf16x8 ab1 = *(const bf16x8*)Apb1;
    __builtin_amdgcn_sched_barrier(0);
    {
        char* d0 = (char*)smem + t * 16;
#pragma unroll
        for (int i = 0; i < 4; i++) gl_lds16(Pb + i * 4096, d0 + i * 4096);
        char* d1 = (char*)smem + 16384 + t * 16;
#pragma unroll
        for (int i = 0; i < 4; i++) gl_lds16(Pb + 16384 + i * 4096, d1 + i * 4096);
    }
    __builtin_amdgcn_sched_barrier(0);

    int slot = 0;
    for (int c = 0; c < NC; ++c) {
        if (c == 0)
            asm volatile("s_waitcnt vmcnt(4)" ::: "memory");
        else if (c == NC - 1)
            asm volatile("s_waitcnt vmcnt(%0)" :: "i"(AOPS) : "memory");
        else
            asm volatile("s_waitcnt vmcnt(%0)" :: "i"(AOPS + 4) : "memory");
        __builtin_amdgcn_s_barrier();
        __builtin_amdgcn_sched_barrier(0);

        bf16x8 nb0 = ab0, nb1 = ab1;
        if (c + 1 < NC) {
            nb0 = *(const bf16x8*)(Apb0 + (c + 1) * 32);
            nb1 = *(const bf16x8*)(Apb1 + (c + 1) * 32);
        }
        __builtin_amdgcn_sched_barrier(0);
        if (c + 2 < NC) {
            int nq = slot + 16384;
            if (nq >= 24576) nq -= 24576;
            const char* src = (const char*)P + (size_t)(c + 2) * 16384 + t * 16;
            char* d = (char*)smem + (size_t)nq * 2 + t * 16;
#pragma unroll
            for (int i = 0; i < 4; i++) gl_lds16(src + i * 4096, d + i * 4096);
        }
        __builtin_amdgcn_sched_barrier(0);

        bf16x8 bh[8], bl[8];
#pragma unroll
        for (int f = 0; f < 8; f++)
            bh[f] = *(const bf16x8*)&smem[slot + f * 512 + l * 8];
#pragma unroll
        for (int f = 0; f < 8; f++)
            bl[f] = *(const bf16x8*)&smem[slot + 4096 + f * 512 + l * 8];

        bf16x8 h0 = relu8(ab0);
        bf16x8 h1 = relu8(ab1);
#pragma unroll
        for (int f = 0; f < 8; f++) {
            acc[0][f] = __builtin_amdgcn_mfma_f32_16x16x32_bf16(h0, bh[f], acc[0][f], 0, 0, 0);
            acc[1][f] = __builtin_amdgcn_mfma_f32_16x16x32_bf16(h1, bh[f], acc[1][f], 0, 0, 0);
        }
#pragma unroll
        for (int f = 0; f < 8; f++) {
            acc[0][f] = __builtin_amdgcn_mfma_f32_16x16x32_bf16(h0, bl[f], acc[0][f], 0, 0, 0);
            acc[1][f] = __builtin_amdgcn_mfma_f32_16x16x32_bf16(h1, bl[f], acc[1][f], 0, 0, 0);
        }

        ab0 = nb0; ab1 = nb1;
        slot += 8192;
        if (slot >= 24576) slot = 0;
    }
    __syncthreads();

    u16* lds = smem + w * 4224;
#pragma unroll
    for (int s = 0; s < 2; s++) {
#pragma unroll
        for (int j = 0; j < 4; j++) {
            int rl = s * 16 + lq * 4 + j;
            int grow = m0 + w * 32 + rl;
            int gs = grow < M ? grow : M - 1;
            float scale = dinv[gs];
#pragma unroll
            for (int f = 0; f < 8; f++)
                lds[rl * 132 + f * 16 + l16] = f2bf(acc[s][f][j] * scale);
        }
    }
#pragma unroll
    for (int pass = 0; pass < 8; pass++) {
        int row = pass * 4 + lq;
        bf16x8 v = *(const bf16x8*)&lds[row * 132 + l16 * 8];
        *(bf16x8*)&Cbf[(size_t)(m0 + w * 32 + row) * HID + l16 * 8] = v;
    }
}

// ---------------------------------------------------------------------------
// gather aggregation, HALF-WAVE per node (32 lanes, 2 u32 cols/lane):
//   o[d] = bias + dinv[d]*(u[d] + sum u[src])
// Per-column accumulation order identical to R17 -> MODE 0 bitwise-identical.
// 8/4/1 edge unroll; per-lane uint2 loads double outstanding bytes.
// MODE 0: write o as packed bf16 (uint2/lane).  MODE 1: fused output head
// (width-32 shuffle reduce; tree reorder = f32 noise only).
// ---------------------------------------------------------------------------
template <int MODE>
__global__ __launch_bounds__(512)
void agg_gather(const u32* __restrict__ u, const float* __restrict__ dinv,
                const int* __restrict__ row_start, const int* __restrict__ csr_src,
                const float* __restrict__ bias, u32* __restrict__ outbf,
                const float* __restrict__ Wout, const float* __restrict__ bout,
                float* __restrict__ logits) {
    int node = blockIdx.x * 16 + (threadIdx.x >> 5);
    int lane = threadIdx.x & 31;
    if (node >= NN) return;
    int p = row_start[node], pend = row_start[node + 1];
    u32x2 pv = *(const u32x2*)&u[(size_t)node * 64 + lane * 2];
    float a0 = __builtin_bit_cast(float, pv[0] << 16);
    float a1 = __builtin_bit_cast(float, pv[0] & 0xFFFF0000u);
    float a2 = __builtin_bit_cast(float, pv[1] << 16);
    float a3 = __builtin_bit_cast(float, pv[1] & 0xFFFF0000u);
    int p8 = p + ((pend - p) & ~7);
    for (; p < p8; p += 8) {
        int s0 = csr_src[p],     s1 = csr_src[p + 1];
        int s2 = csr_src[p + 2], s3 = csr_src[p + 3];
        int s4 = csr_src[p + 4], s5 = csr_src[p + 5];
        int s6 = csr_src[p + 6], s7 = csr_src[p + 7];
        u32x2 v0 = *(const u32x2*)&u[(size_t)s0 * 64 + lane * 2];
        u32x2 v1 = *(const u32x2*)&u[(size_t)s1 * 64 + lane * 2];
        u32x2 v2 = *(const u32x2*)&u[(size_t)s2 * 64 + lane * 2];
        u32x2 v3 = *(const u32x2*)&u[(size_t)s3 * 64 + lane * 2];
        u32x2 v4 = *(const u32x2*)&u[(size_t)s4 * 64 + lane * 2];
        u32x2 v5 = *(const u32x2*)&u[(size_t)s5 * 64 + lane * 2];
        u32x2 v6 = *(const u32x2*)&u[(size_t)s6 * 64 + lane * 2];
        u32x2 v7 = *(const u32x2*)&u[(size_t)s7 * 64 + lane * 2];
#define ACC2(vv)                                              \
        a0 += __builtin_bit_cast(float, (vv)[0] << 16);       \
        a1 += __builtin_bit_cast(float, (vv)[0] & 0xFFFF0000u); \
        a2 += __builtin_bit_cast(float, (vv)[1] << 16);       \
        a3 += __builtin_bit_cast(float, (vv)[1] & 0xFFFF0000u);
        ACC2(v0) ACC2(v1) ACC2(v2) ACC2(v3)
        ACC2(v4) ACC2(v5) ACC2(v6) ACC2(v7)
    }
    int p4 = p + ((pend - p) & ~3);
    for (; p < p4; p += 4) {
        int s0 = csr_src[p],     s1 = csr_src[p + 1];
        int s2 = csr_src[p + 2], s3 = csr_src[p + 3];
        u32x2 v0 = *(const u32x2*)&u[(size_t)s0 * 64 + lane * 2];
        u32x2 v1 = *(const u32x2*)&u[(size_t)s1 * 64 + lane * 2];
        u32x2 v2 = *(const u32x2*)&u[(size_t)s2 * 64 + lane * 2];
        u32x2 v3 = *(const u32x2*)&u[(size_t)s3 * 64 + lane * 2];
        ACC2(v0) ACC2(v1) ACC2(v2) ACC2(v3)
    }
    for (; p < pend; ++p) {
        int s = csr_src[p];
        u32x2 v = *(const u32x2*)&u[(size_t)s * 64 + lane * 2];
        ACC2(v)
    }
#undef ACC2
    float dd = dinv[node];
    float4 bb = *(const float4*)&bias[lane * 4];
    float o0 = fmaf(dd, a0, bb.x);
    float o1 = fmaf(dd, a1, bb.y);
    float o2 = fmaf(dd, a2, bb.z);
    float o3 = fmaf(dd, a3, bb.w);
    if (MODE == 1) {
        float4 wv = *(const float4*)&Wout[lane * 4];
        float v = fmaxf(o0, 0.f) * wv.x + fmaxf(o1, 0.f) * wv.y +
                  fmaxf(o2, 0.f) * wv.z + fmaxf(o3, 0.f) * wv.w;
#pragma unroll
        for (int o = 16; o; o >>= 1) v += __shfl_down(v, o, 32);
        if (lane == 0) logits[node] = v + bout[0];
    } else {
        u32x2 r;
        r[0] = cvtpk(o0, o1);
        r[1] = cvtpk(o2, o3);
        *(u32x2*)&outbf[(size_t)node * 64 + lane * 2] = r;
    }
}

// ---------------------------------------------------------------------------
extern "C" void kernel_launch(void* const* d_in, const int* in_sizes, int n_in,
                              void* d_out, int out_size, void* d_ws, size_t ws_size,
                              hipStream_t stream) {
    const float* x     = (const float*)d_in[0];
    const int*   ei    = (const int*)d_in[1];
    const float* se    = (const float*)d_in[2];
    const int*   batch = (const int*)d_in[3];
    const float* W1    = (const float*)d_in[4];
    const float* b1    = (const float*)d_in[5];
    const float* W2    = (const float*)d_in[6];
    const float* b2    = (const float*)d_in[7];
    const float* Wout  = (const float*)d_in[8];
    const float* bout  = (const float*)d_in[9];
    float* logits = (float*)d_out;

    const int* srcp = ei;
    const int* dstp = ei + NE;

    // workspace carve (float offsets; 16B-aligned)
    float* ws       = (float*)d_ws;
    float* dinv     = ws;                        // 50176
    float* condW    = ws + 50176;                // 8192
    u16*   W1p      = (u16*)(ws + 58368);        // 98304 f
    u16*   W2p      = (u16*)(ws + 156672);       // 16384 f
    int*   counts   = (int*)(ws + 173056);       // 50176 (reused as cursor)
    int*   row_st   = (int*)(ws + 223232);       // 50176
    int*   csr_src  = (int*)(ws + 273408);       // 600000
    int*   bsum     = (int*)(ws + 873408);       // 256
    float* bufA     = ws + 873664;               // NNP*128 f region

    u16* ubf  = (u16*)bufA;                      // u (bf16), both layers
    u16* h1bf = (u16*)(bufA + (size_t)NNP * 64); // h1 (bf16)

    const int NB = (NN + 255) / 256;  // 196

    // fused prep: zero counts | condW | W1 pack | W2 pack  (one dispatch)
    prep_fused<<<190, 512, 0, stream>>>(counts, se, W1, W2, condW, W1p, W2p);

    // degree + CSR build
    deg_count<<<(NE + 255) / 256, 256, 0, stream>>>(dstp, counts);
    pscan1<<<NB, 256, 0, stream>>>(counts, row_st, bsum, dinv);
    pscan23<<<NB, 256, 0, stream>>>(row_st, bsum, counts, NB);
    csr_fill<<<(NE + 255) / 256, 256, 0, stream>>>(srcp, dstp, counts, csr_src);

    const int GB = (NN + 127) / 128;   // 391

    // layer 1 (pipelined, A-depth 3): u1(bf16) = (x @ W1[:768] + cond) * dinv
    mfma_gemm1<<<GB, 256, 0, stream>>>(x, W1p, ubf, condW, batch, dinv, NN);
    agg_gather<0><<<(NN + 15) / 16, 512, 0, stream>>>(
        (const u32*)ubf, dinv, row_st, csr_src, b1, (u32*)h1bf,
        nullptr, nullptr, nullptr);

    // layer 2 (pipelined): u2(bf16) = (relu(h1bf) @ W2) * dinv ; gather + head
    mfma_gemm2<<<GB, 256, 0, stream>>>(h1bf, W2p, ubf, dinv, NN);
    agg_gather<1><<<(NN + 15) / 16, 512, 0, stream>>>(
        (const u32*)ubf, dinv, row_st, csr_src, b2, nullptr, Wout, bout, logits);
}